// Round 6
// baseline (493.669 us; speedup 1.0000x reference)
//
#include <hip/hip_runtime.h>
#include <math.h>

#define DD 512
#define HG 64
#define M_ROWS 32768                    // 8*64*64
#define ELEMS ((size_t)M_ROWS * DD)
#define LOG2E 1.44269504088896340736f

typedef __attribute__((ext_vector_type(8))) _Float16 f16x8;
typedef __attribute__((ext_vector_type(2))) _Float16 f16x2;
typedef __attribute__((ext_vector_type(4))) float f32x4;

__device__ __forceinline__ float fexp2_(float x) { return __builtin_amdgcn_exp2f(x); }
__device__ __forceinline__ float frcp_(float x)  { return __builtin_amdgcn_rcpf(x); }
// sigmoid(v) = 1/(1+exp2(-v*log2e)); inf-safe: exp2->inf => rcp->0
__device__ __forceinline__ float fsig_(float v)  { return frcp_(1.0f + fexp2_(-v * LOG2E)); }

// Fused prep: blocks [0,8192) convert x fp32->fp16; blocks [8192,8448)
// transpose+convert the four 512x512 weights into WT (fp16, N-major).
__global__ __launch_bounds__(256) void prep(
    const float* __restrict__ x, _Float16* __restrict__ x16,
    const float* __restrict__ W0, const float* __restrict__ W1,
    const float* __restrict__ W2, const float* __restrict__ W3,
    _Float16* __restrict__ WT)
{
    __shared__ float tile[64][65];
    if (blockIdx.x < 8192) {
        const size_t i = ((size_t)blockIdx.x * 256 + threadIdx.x) * 8;
        const float4 a = *(const float4*)&x[i];
        const float4 b = *(const float4*)&x[i + 4];
        f16x8 h;
        h[0] = (_Float16)a.x; h[1] = (_Float16)a.y;
        h[2] = (_Float16)a.z; h[3] = (_Float16)a.w;
        h[4] = (_Float16)b.x; h[5] = (_Float16)b.y;
        h[6] = (_Float16)b.z; h[7] = (_Float16)b.w;
        *(f16x8*)&x16[i] = h;
        return;
    }
    const int wb = blockIdx.x - 8192;       // 0..255
    const int z = wb >> 6;
    const int rem = wb & 63;
    const int n0 = (rem & 7) * 64, k0 = (rem >> 3) * 64;
    const float* W = (z == 0) ? W0 : (z == 1) ? W1 : (z == 2) ? W2 : W3;
    _Float16* dst = WT + (size_t)z * DD * DD;
    const int t = threadIdx.x;
    const int tr = t >> 6, tc = t & 63;
#pragma unroll
    for (int p = 0; p < 16; ++p)
        tile[p * 4 + tr][tc] = W[(size_t)(k0 + p * 4 + tr) * DD + n0 + tc];
    __syncthreads();
#pragma unroll
    for (int p = 0; p < 16; ++p) {
        const int nn = p * 4 + tr;
        dst[(size_t)(n0 + nn) * DD + k0 + tc] = (_Float16)tile[tc][nn];
    }
}

// fp16 GEMM, 128x128 tile, BK=64 as two [128][32] XOR-swizzled stages.
// MODE 0: A=x16, WT=[W_f|W_in|W_g]^T (N=1536), epilogues dm/u/g (fp16).
// MODE 1: A=v, WT=W_out^T, out f32.
template <int MODE>
__global__ __launch_bounds__(256) void gemm_f16(
    const _Float16* __restrict__ A, const _Float16* __restrict__ WT,
    const float* __restrict__ b0, const float* __restrict__ b1,
    const float* __restrict__ b2, const float* __restrict__ lb_ptr,
    void* __restrict__ o0, void* __restrict__ o1, void* __restrict__ o2)
{
    __shared__ __align__(16) _Float16 As[2][128][32];
    __shared__ __align__(16) _Float16 Bs[2][128][32];

    const int NB = (MODE == 0) ? 12 : 4;
    const int lin = blockIdx.x;
    const int xcd = lin & 7;
    const int n_idx = (lin >> 3) % NB;
    const int mq = lin / (8 * NB);
    const int m0 = (xcd + 8 * mq) * 128;      // same XCD -> same A strip
    const int n0 = n_idx * 128;

    const int tid  = threadIdx.x;
    const int wave = tid >> 6;
    const int lane = tid & 63;
    const int wm = wave >> 1, wn = wave & 1;
    const int lrow = lane & 15;
    const int lk   = lane >> 4;

    // async staging slot: row lane>>2, col8 lane&3; source col8 XOR-swizzled
    // so LDS[r][c8] = G[r][c8 ^ ((r>>1)&3)]  (proven 0-conflict layout)
    const int srow  = lane >> 2;
    const int skoff = ((lane & 3) ^ ((lane >> 3) & 3)) * 8;
    const int ksw   = (lk ^ ((lrow >> 1) & 3)) * 8;

    f32x4 acc[4][4];
#pragma unroll
    for (int i = 0; i < 4; ++i)
#pragma unroll
        for (int j = 0; j < 4; ++j) acc[i][j] = (f32x4)(0.f);

    for (int k0 = 0; k0 < DD; k0 += 64) {
#pragma unroll
        for (int h = 0; h < 2; ++h) {
#pragma unroll
            for (int i = 0; i < 2; ++i) {
                const int row = wave * 32 + i * 16;
                const _Float16* bsrc =
                    WT + (size_t)(n0 + row + srow) * DD + k0 + h * 32 + skoff;
                __builtin_amdgcn_global_load_lds(
                    (const __attribute__((address_space(1))) void*)bsrc,
                    (__attribute__((address_space(3))) void*)&Bs[h][row][0], 16, 0, 0);
                const _Float16* asrc =
                    A + (size_t)(m0 + row + srow) * DD + k0 + h * 32 + skoff;
                __builtin_amdgcn_global_load_lds(
                    (const __attribute__((address_space(1))) void*)asrc,
                    (__attribute__((address_space(3))) void*)&As[h][row][0], 16, 0, 0);
            }
        }
        __syncthreads();
#pragma unroll
        for (int h = 0; h < 2; ++h) {
            f16x8 afr[4], bfr[4];
#pragma unroll
            for (int t = 0; t < 4; ++t) {
                afr[t] = *(const f16x8*)&As[h][wm * 64 + t * 16 + lrow][ksw];
                bfr[t] = *(const f16x8*)&Bs[h][wn * 64 + t * 16 + lrow][ksw];
            }
#pragma unroll
            for (int mt = 0; mt < 4; ++mt)
#pragma unroll
                for (int nt = 0; nt < 4; ++nt)
                    acc[mt][nt] = __builtin_amdgcn_mfma_f32_16x16x32_f16(
                        afr[mt], bfr[nt], acc[mt][nt], 0, 0, 0);
        }
        __syncthreads();
    }

    if (MODE == 0) {
        const int seg = n_idx >> 2;
        const float lbv = lb_ptr[0];
        const float* bias = (seg == 0) ? b0 : (seg == 1) ? b1 : b2;
        _Float16* outp = (seg == 0) ? (_Float16*)o0
                       : (seg == 1) ? (_Float16*)o1 : (_Float16*)o2;
        const int cb = (n_idx & 3) * 128 + wn * 64;
#pragma unroll
        for (int mt = 0; mt < 4; ++mt) {
#pragma unroll
            for (int nt = 0; nt < 4; ++nt) {
                const int col = cb + nt * 16 + lrow;
                const float bcol = bias[col];
#pragma unroll
                for (int r = 0; r < 4; ++r) {
                    const int row = m0 + wm * 64 + mt * 16 + lk * 4 + r;
                    const float v = acc[mt][nt][r] + bcol;
                    float res;
                    if (seg == 0)      res = (1.0f - lbv) * frcp_(1.0f + fexp2_(v * LOG2E));
                    else if (seg == 1) res = v * fsig_(v);
                    else               res = fsig_(v);
                    outp[(size_t)row * DD + col] = (_Float16)res;
                }
            }
        }
    } else {
        float* outp = (float*)o0;
#pragma unroll
        for (int mt = 0; mt < 4; ++mt) {
#pragma unroll
            for (int nt = 0; nt < 4; ++nt) {
                const int col = n0 + wn * 64 + nt * 16 + lrow;
                const float bcol = b0[col];
#pragma unroll
                for (int r = 0; r < 4; ++r) {
                    const int row = m0 + wm * 64 + mt * 16 + lk * 4 + r;
                    outp[(size_t)row * DD + col] = acc[mt][nt][r] + bcol;
                }
            }
        }
    }
}

// Both bidirectional scans, ONE d-lane per thread (low VGPR -> occupancy).
// Blocks [0,1024): axis-1 (j) -> ha.  Blocks [1024,2048): axis-0 (i) -> hb.
// lam = 1-dm, inp = dm*u; out = inclusive fwd + inclusive bwd.
__global__ __launch_bounds__(256) void scan2(
    const _Float16* __restrict__ dm, const _Float16* __restrict__ u,
    const float* __restrict__ theta,
    _Float16* __restrict__ ha, _Float16* __restrict__ hb)
{
    const bool is_i = blockIdx.x >= 1024;
    const int t = ((blockIdx.x & 1023) << 8) | threadIdx.x;  // 0..262143
    const int d = t & (DD - 1);
    const int line = t >> 9;           // 0..511
    size_t base, stride;
    _Float16* hout;
    if (!is_i) {
        base = (size_t)line * (HG * DD) + d; stride = DD; hout = ha;
    } else {
        const int bb = line >> 6, j = line & 63;
        base = (size_t)bb * (HG * HG * DD) + (size_t)j * DD + d;
        stride = (size_t)HG * DD; hout = hb;
    }
    float s, c;
    sincosf(theta[d], &s, &c);

    f16x2 fr[HG / 2];                  // fwd results, packed: 32 VGPRs
    float yr = 0.f, yi = 0.f;
#pragma unroll
    for (int k = 0; k < HG; ++k) {
        const size_t idx = base + (size_t)k * stride;
        const float dmv = (float)dm[idx];
        const float lm = 1.0f - dmv;
        const float xv = dmv * (float)u[idx];
        const float nr = fmaf(lm, c * yr - s * yi, xv);
        yi = lm * (c * yi + s * yr);
        yr = nr;
        fr[k >> 1][k & 1] = (_Float16)yr;
    }
    yr = 0.f; yi = 0.f;
#pragma unroll
    for (int k = HG - 1; k >= 0; --k) {
        const size_t idx = base + (size_t)k * stride;
        const float dmv = (float)dm[idx];
        const float lm = 1.0f - dmv;
        const float xv = dmv * (float)u[idx];
        const float nr = fmaf(lm, c * yr - s * yi, xv);
        yi = lm * (c * yi + s * yr);
        yr = nr;
        hout[idx] = (_Float16)((float)fr[k >> 1][k & 1] + yr);
    }
}

// v = g * (ha+hb) * rsqrt(mean((ha+hb)^2)+1e-6), fp16. One block per row.
__global__ __launch_bounds__(256) void gate_rmsnorm(
    const _Float16* __restrict__ ha, const _Float16* __restrict__ hb,
    const _Float16* __restrict__ g, _Float16* __restrict__ v)
{
    const int row = blockIdx.x;
    const int t = threadIdx.x;
    const size_t b0 = (size_t)row * DD + t * 2;
    const f16x2 a = *(const f16x2*)&ha[b0];
    const f16x2 b = *(const f16x2*)&hb[b0];
    const float h0 = (float)a[0] + (float)b[0];
    const float h1 = (float)a[1] + (float)b[1];
    float ss = h0 * h0 + h1 * h1;
#pragma unroll
    for (int off = 32; off > 0; off >>= 1) ss += __shfl_down(ss, off, 64);
    __shared__ float wsum[4];
    __shared__ float rms_s;
    if ((t & 63) == 0) wsum[t >> 6] = ss;
    __syncthreads();
    if (t == 0) {
        const float tot = wsum[0] + wsum[1] + wsum[2] + wsum[3];
        rms_s = rsqrtf(tot * (1.0f / (float)DD) + 1e-6f);
    }
    __syncthreads();
    const float rms = rms_s;
    const f16x2 gg = *(const f16x2*)&g[b0];
    f16x2 o;
    o[0] = (_Float16)((float)gg[0] * h0 * rms);
    o[1] = (_Float16)((float)gg[1] * h1 * rms);
    *(f16x2*)&v[b0] = o;
}

extern "C" void kernel_launch(void* const* d_in, const int* in_sizes, int n_in,
                              void* d_out, int out_size, void* d_ws, size_t ws_size,
                              hipStream_t stream)
{
    const float* x     = (const float*)d_in[0];
    const float* lb    = (const float*)d_in[1];
    const float* W_in  = (const float*)d_in[2];
    const float* b_in  = (const float*)d_in[3];
    const float* W_f   = (const float*)d_in[4];
    const float* b_f   = (const float*)d_in[5];
    const float* theta = (const float*)d_in[6];
    const float* W_g   = (const float*)d_in[7];
    const float* b_g   = (const float*)d_in[8];
    const float* W_out = (const float*)d_in[9];
    const float* b_out = (const float*)d_in[10];

    float* out = (float*)d_out;
    char* wsb  = (char*)d_ws;

    // ws (98 MB): [0,32M) dm fp16 (later v)  [32M,64M) u fp16
    //             [64M,96M) g fp16           [96M,98M) WT fp16 [2048][512]
    _Float16* dm_v = (_Float16*)wsb;
    _Float16* u_b  = (_Float16*)(wsb + ELEMS * 2);
    _Float16* g_b  = (_Float16*)(wsb + ELEMS * 4);
    _Float16* WT   = (_Float16*)(wsb + ELEMS * 6);
    const size_t WSEG = (size_t)DD * DD;

    // d_out doubles as scratch: [0,32M) ha fp16; [32M,64M) x16, then hb fp16.
    _Float16* ha  = (_Float16*)d_out;
    _Float16* x16 = (_Float16*)((char*)d_out + ELEMS * 2);
    _Float16* hb  = x16;                 // x16 dead after gemm_f16<0>

    prep<<<8448, 256, 0, stream>>>(x, x16, W_f, W_in, W_g, W_out, WT);

    gemm_f16<0><<<3072, 256, 0, stream>>>(x16, WT, b_f, b_in, b_g, lb,
                                          dm_v, u_b, g_b);

    scan2<<<2048, 256, 0, stream>>>(dm_v, u_b, theta, ha, hb);

    // v overwrites dm (dead after scan2)
    gate_rmsnorm<<<M_ROWS, 256, 0, stream>>>(ha, hb, g_b, dm_v);

    // out = v @ W_out^T + b_out  (overwrites all of d_out)
    gemm_f16<1><<<1024, 256, 0, stream>>>(dm_v, WT + 3 * WSEG, b_out, nullptr,
                                          nullptr, nullptr, out, nullptr, nullptr);
}